// Round 8
// baseline (115.606 us; speedup 1.0000x reference)
//
#include <hip/hip_runtime.h>
#include <hip/hip_bf16.h>
#include <math.h>

#define ALPHA 0.01f

// ---------------------------------------------------------------------------
// Per-block frv recompute (32 threads): frv[l][p] = product of normalized
// rvec[l..2][p] (ETYPES=(0,2,4) selects rv2[0,2,4] = rv[0,1,2]); frv[3]=1+0j.
// frvs layout: l*64 + p*2 + c.
// ---------------------------------------------------------------------------
__device__ __forceinline__ void compute_frv_block(const float* __restrict__ rvec,
                                                  float* __restrict__ frvs,
                                                  int tid) {
    if (tid < 32) {
        int p = tid;
        float fr = 1.f, fi = 0.f;
        frvs[3 * 64 + 2 * p]     = 1.f;
        frvs[3 * 64 + 2 * p + 1] = 0.f;
        for (int l = 2; l >= 0; --l) {
            float rr = rvec[l * 64 + 2 * p];
            float ri = rvec[l * 64 + 2 * p + 1];
            float inv = rsqrtf(rr * rr + ri * ri);
            rr *= inv; ri *= inv;
            float nr = fr * rr - fi * ri;
            float ni = fr * ri + fi * rr;
            fr = nr; fi = ni;
            frvs[l * 64 + 2 * p]     = fr;
            frvs[l * 64 + 2 * p + 1] = fi;
        }
    }
}

// ---------------------------------------------------------------------------
// prep: fused out0 + per-node logit tables + edge histogram (counts zeroed
// by hipMemsetAsync before this kernel; histo is grid-strided over E and
// runs before the early-exit so all threads cover their edge range).
//   q[n][0..7]   = feat[n]·w1[h]
//   q[n][8+l*8+h]= 0.25 * feat[n]·(rot_l^* w2[h])
// ONE node per thread (acc[10] float4 = 40 VGPRs; 2-node variant spilled).
// ---------------------------------------------------------------------------
__global__ void prep_kernel(const float* __restrict__ feat,
                            const float* __restrict__ w1,
                            const float* __restrict__ w2,
                            const float* __restrict__ rvec,
                            const int* __restrict__ ift,
                            const int* __restrict__ mp,
                            float* __restrict__ out0,
                            float* __restrict__ q,
                            int* __restrict__ counts, int N, int E) {
    __shared__ float frvs[256];
    __shared__ float wt[64 * 40];
    int tid = threadIdx.x;
    compute_frv_block(rvec, frvs, tid);

    // edge histogram (before any early exit; counts pre-zeroed)
    int gsz = gridDim.x * blockDim.x;
    for (int e = blockIdx.x * blockDim.x + tid; e < E; e += gsz)
        atomicAdd(&counts[((const int4*)mp)[e].w], 1);

    __syncthreads();
    for (int i = tid; i < 512; i += 256) {          // w1 part
        int h = i >> 6, d = i & 63;
        wt[d * 40 + h] = w1[i];
    }
    for (int i = tid; i < 2048; i += 256) {         // rotated w2 part
        int l = i >> 9, r = i & 511, h = r >> 6, d = r & 63;
        float fr = frvs[l * 64 + (d & ~1)];
        float fi = frvs[l * 64 + (d | 1)];
        float sgn = (d & 1) ? -1.f : 1.f;
        float v = w2[h * 64 + d] * fr + sgn * w2[h * 64 + (d ^ 1)] * fi;
        wt[d * 40 + 8 + l * 8 + h] = 0.25f * v;
    }
    __syncthreads();

    int n = blockIdx.x * 256 + tid;
    if (n >= N) return;
    out0[n] = (float)ift[2 * (size_t)n];

    float4 acc[10];
#pragma unroll
    for (int k = 0; k < 10; ++k) acc[k] = make_float4(0.f, 0.f, 0.f, 0.f);
    const float4* row = (const float4*)(feat + (size_t)n * 64);
#pragma unroll
    for (int dd = 0; dd < 16; ++dd) {
        float4 x4 = row[dd];
        float cx[4] = {x4.x, x4.y, x4.z, x4.w};
#pragma unroll
        for (int c = 0; c < 4; ++c) {
            const float4* w4 = (const float4*)(wt + (dd * 4 + c) * 40);
            float x = cx[c];
#pragma unroll
            for (int k = 0; k < 10; ++k) {
                float4 w = w4[k];
                acc[k].x += x * w.x; acc[k].y += x * w.y;
                acc[k].z += x * w.z; acc[k].w += x * w.w;
            }
        }
    }
    float4* qo = (float4*)(q + (size_t)n * 40);
#pragma unroll
    for (int k = 0; k < 10; ++k) qo[k] = acc[k];
}

// ---------------------------------------------------------------------------
// hierarchical scan, 256-element chunks.
// ---------------------------------------------------------------------------
__global__ void scan1_kernel(const int* __restrict__ counts,
                             int* __restrict__ offsets,
                             int* __restrict__ bsums, int N) {
    __shared__ int tmp[256];
    int tid = threadIdx.x;
    int gid = blockIdx.x * 256 + tid;
    int v = (gid < N) ? counts[gid] : 0;
    tmp[tid] = v;
    __syncthreads();
#pragma unroll
    for (int ofs = 1; ofs < 256; ofs <<= 1) {
        int t = (tid >= ofs) ? tmp[tid - ofs] : 0;
        __syncthreads();
        tmp[tid] += t;
        __syncthreads();
    }
    if (gid < N) offsets[gid] = tmp[tid] - v;      // exclusive, block-local
    if (tid == 255) bsums[blockIdx.x] = tmp[255];
}

__global__ void scan2_kernel(int* __restrict__ bsums, int B) {
    __shared__ int tmp[256];
    int tid = threadIdx.x;
    int v = (tid < B) ? bsums[tid] : 0;
    tmp[tid] = v;
    __syncthreads();
#pragma unroll
    for (int ofs = 1; ofs < 256; ofs <<= 1) {
        int t = (tid >= ofs) ? tmp[tid - ofs] : 0;
        __syncthreads();
        tmp[tid] += t;
        __syncthreads();
    }
    if (tid < B) bsums[tid] = tmp[tid] - v;        // exclusive block prefix
}

__global__ void scan3_kernel(int* __restrict__ offsets,
                             int* __restrict__ cursor,
                             const int* __restrict__ bsums, int N, int E) {
    int gid = blockIdx.x * 256 + threadIdx.x;
    if (gid < N) {
        int o = offsets[gid] + bsums[gid >> 8];
        offsets[gid] = o;
        cursor[gid]  = o;
    }
    if (gid == 0) offsets[N] = E;
}

// ---------------------------------------------------------------------------
// edge_scatter: fused logits + CSR permute. a[h] = leaky(q1[dst][h] +
// sum_l q2[src_l][l][h]); pos = cursor[dst]++; write mpperm/aperm at pos.
// ---------------------------------------------------------------------------
__global__ void edge_scatter_kernel(const int* __restrict__ mp,
                                    const float* __restrict__ q,
                                    int* __restrict__ cursor,
                                    int* __restrict__ mpperm,
                                    float* __restrict__ aperm, int E) {
    int e = blockIdx.x * blockDim.x + threadIdx.x;
    if (e >= E) return;
    const int4 m4 = ((const int4*)mp)[e];
    const float4* qc = (const float4*)(q + (size_t)m4.w * 40);
    float4 a0 = qc[0], a1 = qc[1];
    int idx[4] = {m4.x, m4.y, m4.z, m4.w};
#pragma unroll
    for (int l = 0; l < 4; ++l) {
        const float4* ql = (const float4*)(q + (size_t)idx[l] * 40 + 8 + l * 8);
        float4 b0 = ql[0], b1 = ql[1];
        a0.x += b0.x; a0.y += b0.y; a0.z += b0.z; a0.w += b0.w;
        a1.x += b1.x; a1.y += b1.y; a1.z += b1.z; a1.w += b1.w;
    }
    a0.x = a0.x > 0.f ? a0.x : ALPHA * a0.x;
    a0.y = a0.y > 0.f ? a0.y : ALPHA * a0.y;
    a0.z = a0.z > 0.f ? a0.z : ALPHA * a0.z;
    a0.w = a0.w > 0.f ? a0.w : ALPHA * a0.w;
    a1.x = a1.x > 0.f ? a1.x : ALPHA * a1.x;
    a1.y = a1.y > 0.f ? a1.y : ALPHA * a1.y;
    a1.z = a1.z > 0.f ? a1.z : ALPHA * a1.z;
    a1.w = a1.w > 0.f ? a1.w : ALPHA * a1.w;
    int pos = atomicAdd(&cursor[m4.w], 1);
    ((int4*)mpperm)[pos] = m4;
    float4* ap = (float4*)(aperm + (size_t)pos * 8);
    ap[0] = a0; ap[1] = a1;
}

// ---------------------------------------------------------------------------
// node: one wave per node.
//  - expsum WITHOUT max (logits bounded; exact in fp32), attc cache in LDS.
//  - l=3 leg eliminated: rot_3 = identity and mp[e][3]==wid, and since
//    sum_e attnorm = 1, center contributes exactly 0.25*feat[wid] per head.
//  - pair lanes: lane=(half,pair); float2 loads, complex mul in-lane (no
//    shuffles in loop), 2 edges per load inst, 4 edges/iter.
//  - epilogue: stride-9 float2 LDS transpose (bank-conflict-free), 2x float4
//    contiguous stores per lane.
// ---------------------------------------------------------------------------
#define CAP 32
__global__ __launch_bounds__(256, 4)
void node_kernel(const float* __restrict__ feat,
                 const float* __restrict__ rvec,
                 const float* __restrict__ aperm,
                 const int* __restrict__ mpperm,
                 const int* __restrict__ offsets,
                 float* __restrict__ ft, int N) {
    __shared__ float frvs[256];
    __shared__ float rs[4][8];
    __shared__ float attc[4][CAP][8];
    __shared__ float2 ftt2[4][32 * 9];
    int tid = threadIdx.x;
    compute_frv_block(rvec, frvs, tid);
    __syncthreads();

    int wid = (int)((blockIdx.x * blockDim.x + tid) >> 6);
    int lane = tid & 63;
    int w = tid >> 6;
    if (wid >= N) return;
    int beg = offsets[wid], end = offsets[wid + 1];

    // ---- expsum (no max) + attc cache; 64 lanes cover 8 edges/iter ----
    int h = lane & 7;
    float s = 0.f;
    {
        int j = lane >> 3;
        for (int idx = beg * 8 + lane; idx < end * 8; idx += 64, j += 8) {
            float ev = __expf(aperm[idx]);
            s += ev;
            if (j < CAP) attc[w][j][h] = ev;
        }
    }
    s += __shfl_xor(s, 8);
    s += __shfl_xor(s, 16);
    s += __shfl_xor(s, 32);
    if (lane < 8) rs[w][lane] = (s > 0.f) ? 1.f / s : 0.f;
    // same-wave LDS write->read; compiler inserts lgkmcnt waits

    // ---- pair-based aggregation ----
    int half = lane >> 5;          // which edge of the pair
    int pr   = lane & 31;          // complex pair index (d = 2*pr, 2*pr+1)
    float fr0[3], fi0[3];
#pragma unroll
    for (int l = 0; l < 3; ++l) {
        fr0[l] = frvs[l * 64 + pr * 2];
        fi0[l] = frvs[l * 64 + pr * 2 + 1];
    }
    float2 xc = *(const float2*)&feat[(size_t)wid * 64 + pr * 2];

    float2 acc[8];
#pragma unroll
    for (int hh = 0; hh < 8; ++hh) acc[hh] = make_float2(0.f, 0.f);

    for (int p = beg; p < end; p += 4) {
#pragma unroll
        for (int s2 = 0; s2 < 2; ++s2) {
            int ep = p + s2 * 2 + half;
            bool valid = ep < end;
            int epc = valid ? ep : end - 1;
            const int4 m4 = ((const int4*)mpperm)[epc];
            int idx3[3] = {m4.x, m4.y, m4.z};
            float2 hv = make_float2(0.f, 0.f);
#pragma unroll
            for (int l = 0; l < 3; ++l) {
                float2 x = *(const float2*)&feat[(size_t)idx3[l] * 64 + pr * 2];
                hv.x += x.x * fr0[l] - x.y * fi0[l];
                hv.y += x.x * fi0[l] + x.y * fr0[l];
            }
            hv.x = valid ? hv.x * 0.25f : 0.f;
            hv.y = valid ? hv.y * 0.25f : 0.f;
            int j = epc - beg;
            float at[8];
            if (j < CAP) {
                float4 aa = *(const float4*)&attc[w][j][0];
                float4 ab = *(const float4*)&attc[w][j][4];
                at[0] = aa.x; at[1] = aa.y; at[2] = aa.z; at[3] = aa.w;
                at[4] = ab.x; at[5] = ab.y; at[6] = ab.z; at[7] = ab.w;
            } else {
#pragma unroll
                for (int hh = 0; hh < 8; ++hh)
                    at[hh] = __expf(aperm[(size_t)epc * 8 + hh]);
            }
#pragma unroll
            for (int hh = 0; hh < 8; ++hh) {
                acc[hh].x += at[hh] * hv.x;
                acc[hh].y += at[hh] * hv.y;
            }
        }
    }

    // cross-half reduce: both halves end with the full segment sum
#pragma unroll
    for (int hh = 0; hh < 8; ++hh) {
        acc[hh].x += __shfl_xor(acc[hh].x, 32);
        acc[hh].y += __shfl_xor(acc[hh].y, 32);
    }

    float cadd = (end > beg) ? 0.25f : 0.f;   // empty segments output zeros
    if (half == 0) {
#pragma unroll
        for (int hh = 0; hh < 8; ++hh) {
            float r = rs[w][hh];
            float2 v;
            v.x = acc[hh].x * r + cadd * xc.x;
            v.y = acc[hh].y * r + cadd * xc.y;
            ftt2[w][pr * 9 + hh] = v;         // stride-9: conflict-free
        }
    }
    // same-wave LDS write->read
    float2 rr[4];
#pragma unroll
    for (int k2 = 0; k2 < 4; ++k2) {
        int f = lane * 4 + k2;
        rr[k2] = ftt2[w][(f & 31) * 9 + (f >> 5)];
    }
    float4 o0 = make_float4(rr[0].x, rr[0].y, rr[1].x, rr[1].y);
    float4 o1 = make_float4(rr[2].x, rr[2].y, rr[3].x, rr[3].y);
    float4* o = (float4*)(ft + (size_t)wid * 512 + lane * 8);
    o[0] = o0;
    o[1] = o1;
}

extern "C" void kernel_launch(void* const* d_in, const int* in_sizes, int n_in,
                              void* d_out, int out_size, void* d_ws, size_t ws_size,
                              hipStream_t stream) {
    const int*   mp   = (const int*)d_in[0];
    const int*   ift  = (const int*)d_in[1];
    const float* feat = (const float*)d_in[2];
    const float* rvec = (const float*)d_in[3];
    const float* w1   = (const float*)d_in[4];
    const float* w2   = (const float*)d_in[5];
    int E = in_sizes[0] / 4;
    int N = in_sizes[2] / 64;

    float* out0 = (float*)d_out;
    float* ft   = out0 + N;

    float* q       = (float*)d_ws;                         // N*40
    float* aperm   = q + (size_t)N * 40;                   // E*8
    int*   mpperm  = (int*)(aperm + (size_t)E * 8);        // E*4 (16B-aligned)
    int*   counts  = mpperm + (size_t)E * 4;               // N
    int*   offsets = counts + N;                           // N+1
    int*   cursor  = offsets + N + 1;                      // N
    int*   bsums   = cursor + N;                           // nblkN

    int nblkN = (N + 255) / 256;

    hipMemsetAsync(counts, 0, (size_t)N * sizeof(int), stream);
    prep_kernel<<<nblkN, 256, 0, stream>>>(feat, w1, w2, rvec, ift, mp,
                                           out0, q, counts, N, E);
    scan1_kernel<<<nblkN, 256, 0, stream>>>(counts, offsets, bsums, N);
    scan2_kernel<<<1, 256, 0, stream>>>(bsums, nblkN);
    scan3_kernel<<<nblkN, 256, 0, stream>>>(offsets, cursor, bsums, N, E);
    edge_scatter_kernel<<<(E + 255) / 256, 256, 0, stream>>>(mp, q, cursor,
                                                             mpperm, aperm, E);
    node_kernel<<<(N + 3) / 4, 256, 0, stream>>>(feat, rvec, aperm, mpperm,
                                                 offsets, ft, N);
}